// Round 6
// baseline (350.618 us; speedup 1.0000x reference)
//
#include <hip/hip_runtime.h>
#include <math.h>

// ---------------------------------------------------------------------------
// HiPPO-LegS scan via quasiseparable structure of dA.
//
//   A = -(tril(r r^T, -1) + diag(i+1)),  r_i = sqrt(2i+1)
//   dA = (I - (dt/2)A)^-1 (I + (dt/2)A) = 2(I-dX)^-1 - I
// (I - dX) = diag(D) + tril(u v^T, -1)  with D_i = 1+delta(i+1),
//   u_i = delta*r_i, v_j = r_j, delta = dt/2 = 1/8192.
// Inverse keeps the "diag + rank-1 strictly-lower" form (checked by forward
// substitution): G_ij (i>j) = -(u_i/D_i)(v_j/D_j) * W_{i-1}/W_j,
//   W_m = prod_{k<=m} (1 - u_k v_k / D_k).
// So dA = diag(d) + tril(p q^T, -1):
//   p_i = -2 (delta r_i / D_i) W_{i-1},  q_j = (r_j / D_j) / W_j,
//   d_i taken from the GIVEN (7-decimal-rounded) dA diagonal.
// Matvec: dA c = d (*) c + p (*) exclusive_prefix_sum(q (*) c) -> O(N)/step.
//
// 3-phase chunked scan (NCH=16 chunks of CLEN=256 steps):
//   pass1: chunk-local scans (zero init) -> f_k; plus 256 unit columns
//          propagated CLEN steps -> dense M = dA^CLEN (column-major).
//   passB: inc_k = M inc_{k-1} + f_{k-1}. 16 WGs x 4 batch columns; wave w
//          owns a j-quarter, lane loads M column slices as dwordx4
//          (coalesced, deep-pipelined); cross-wave reduce via padded LDS.
//   pass3: rerun local scans from inc_k, store every c_t (write-bound,
//          nontemporal ext-vector stores -- final data, never re-read).
// Scratch lives inside d_out at slots t = k*CLEN+{0,1,2} which the OWNING
// pass3 wave overwrites only after consuming them -> race-free, no d_ws.
// ---------------------------------------------------------------------------

#define L_SEQ 4096
#define BATCH 64
#define NST   256
#define NCH   16
#define CLEN  256   // L_SEQ / NCH
#define RSTR  20    // red[] lane stride (floats): 80 B -> 8 lanes cover all
                    // 32 banks once (gcd(20,32)=4), vs 16 -> banks {0-3,16-19}

typedef float fx4 __attribute__((ext_vector_type(4)));  // nontemporal-capable

template<int CTRL, int RMASK>
__device__ __forceinline__ float dpp_mov_f(float x, float ident) {
  union { float f; int i; } a, b, r;
  a.f = x; b.f = ident;
  r.i = __builtin_amdgcn_update_dpp(b.i, a.i, CTRL, RMASK, 0xF, false);
  return r.f;
}

// wave64 inclusive add-scan: row_shr 1,2,4,8 then row_bcast15 (rows 1,3) and
// row_bcast31 (rows 2,3) -- classic GCN DPP scan, ~6 dependent VALU adds.
__device__ __forceinline__ float wave_iscan_add(float v) {
  v += dpp_mov_f<0x111, 0xF>(v, 0.f);
  v += dpp_mov_f<0x112, 0xF>(v, 0.f);
  v += dpp_mov_f<0x114, 0xF>(v, 0.f);
  v += dpp_mov_f<0x118, 0xF>(v, 0.f);
  v += dpp_mov_f<0x142, 0xA>(v, 0.f);
  v += dpp_mov_f<0x143, 0xC>(v, 0.f);
  return v;
}

template<int CTRL, int RMASK>
__device__ __forceinline__ double dpp_mov_d(double x, double ident) {
  union { double d; int i[2]; } a, b, r;
  a.d = x; b.d = ident;
  r.i[0] = __builtin_amdgcn_update_dpp(b.i[0], a.i[0], CTRL, RMASK, 0xF, false);
  r.i[1] = __builtin_amdgcn_update_dpp(b.i[1], a.i[1], CTRL, RMASK, 0xF, false);
  return r.d;
}

// wave64 inclusive multiplicative scan in fp64 (identity = 1.0)
__device__ __forceinline__ double wave_iscan_mul(double v) {
  v *= dpp_mov_d<0x111, 0xF>(v, 1.0);
  v *= dpp_mov_d<0x112, 0xF>(v, 1.0);
  v *= dpp_mov_d<0x114, 0xF>(v, 1.0);
  v *= dpp_mov_d<0x118, 0xF>(v, 1.0);
  v *= dpp_mov_d<0x142, 0xA>(v, 1.0);
  v *= dpp_mov_d<0x143, 0xC>(v, 1.0);
  return v;
}

// Per-wave parameter build (fp64, ~60 ops, once per wave). Lane l owns
// n = 4l..4l+3. Diagonal d comes from the GIVEN dA (exact vs reference).
__device__ __forceinline__ void compute_params(int lane, const float* __restrict__ dA,
                                               float d[4], float p[4], float q[4]) {
  const double delta = 1.0 / 8192.0;   // dt/2, dt = 1/4096
  double D[4], g[4];
  #pragma unroll
  for (int m = 0; m < 4; ++m) {
    int n = 4 * lane + m;
    D[m] = 1.0 + delta * (double)(n + 1);
    g[m] = 1.0 - delta * (double)(2 * n + 1) / D[m];
  }
  double h01  = g[0] * g[1];
  double h012 = h01 * g[2];
  double h    = h012 * g[3];
  double incl = wave_iscan_mul(h);
  double excl = incl / h;              // W_{4*lane-1} (product over lanes < lane)
  double Wm1[4];
  Wm1[0] = excl;
  Wm1[1] = excl * g[0];
  Wm1[2] = excl * h01;
  Wm1[3] = excl * h012;
  #pragma unroll
  for (int m = 0; m < 4; ++m) {
    int n = 4 * lane + m;
    double r = sqrt(2.0 * (double)n + 1.0);
    double W = Wm1[m] * g[m];
    p[m] = (float)(-2.0 * (delta * r / D[m]) * Wm1[m]);
    q[m] = (float)((r / D[m]) / W);
    d[m] = dA[n * NST + n];
  }
}

// One structured recurrence step: c <- d*c + p*exclprefix(q*c) + in
__device__ __forceinline__ void hippo_step(float& c0, float& c1, float& c2, float& c3,
                                           const float d[4], const float p[4], const float q[4],
                                           float i0, float i1, float i2, float i3) {
  float qc0 = q[0] * c0, qc1 = q[1] * c1, qc2 = q[2] * c2, qc3 = q[3] * c3;
  float t01 = qc0 + qc1, t23 = qc2 + qc3, tot = t01 + t23;
  float s  = wave_iscan_add(tot);
  float e0 = s - tot;                 // exclusive over lanes
  float e1 = e0 + qc0, e2 = e0 + t01, e3 = e2 + qc2;
  c0 = fmaf(d[0], c0, fmaf(p[0], e0, i0));
  c1 = fmaf(d[1], c1, fmaf(p[1], e1, i1));
  c2 = fmaf(d[2], c2, fmaf(p[2], e2, i2));
  c3 = fmaf(d[3], c3, fmaf(p[3], e3, i3));
}

__device__ __forceinline__ float bcast_lane(float v, int l) {
  return __int_as_float(__builtin_amdgcn_readlane(__float_as_int(v), l));
}

// scratch slot addresses inside d_out (overwritten later by the owner wave)
__device__ __forceinline__ size_t inc_addr(int k, int b) {   // incoming state of chunk k
  return ((size_t)(k * CLEN) * BATCH + b) * NST;
}
__device__ __forceinline__ size_t f_addr(int k, int b) {     // local final state of chunk k
  return ((size_t)(k * CLEN + 1) * BATCH + b) * NST;
}
__device__ __forceinline__ size_t mt_addr(int j) {           // column j of M = dA^CLEN
  return ((size_t)((j >> 6) * CLEN + 2) * BATCH + (j & 63)) * NST;
}

// ---- pass 1: chunk-local scans (waves 0..1023) + M columns (waves 1024..1279)
__global__ __launch_bounds__(256) void k_pass1(const float* __restrict__ u,
                                               const float* __restrict__ dA,
                                               const float* __restrict__ dB,
                                               float* __restrict__ out) {
  int wid  = blockIdx.x * 4 + (threadIdx.x >> 6);
  int lane = threadIdx.x & 63;
  float d[4], p[4], q[4];
  compute_params(lane, dA, d, p, q);
  float c0 = 0.f, c1 = 0.f, c2 = 0.f, c3 = 0.f;
  if (wid < NCH * BATCH) {
    int k = wid >> 6, b = wid & 63;
    float4 db = *reinterpret_cast<const float4*>(dB + 4 * lane);
    for (int half = 0; half < CLEN / 64; ++half) {
      float ur = u[(size_t)(k * CLEN + half * 64 + lane) * BATCH + b];
      #pragma unroll 4
      for (int i = 0; i < 64; ++i) {
        float uv = bcast_lane(ur, i);
        hippo_step(c0, c1, c2, c3, d, p, q,
                   db.x * uv, db.y * uv, db.z * uv, db.w * uv);
      }
    }
    *reinterpret_cast<float4*>(out + f_addr(k, b) + 4 * lane) =
        make_float4(c0, c1, c2, c3);
  } else {
    int j = wid - NCH * BATCH;       // unit column j -> dA^CLEN e_j
    c0 = (4 * lane + 0 == j) ? 1.f : 0.f;
    c1 = (4 * lane + 1 == j) ? 1.f : 0.f;
    c2 = (4 * lane + 2 == j) ? 1.f : 0.f;
    c3 = (4 * lane + 3 == j) ? 1.f : 0.f;
    #pragma unroll 4
    for (int i = 0; i < CLEN; ++i)
      hippo_step(c0, c1, c2, c3, d, p, q, 0.f, 0.f, 0.f, 0.f);
    *reinterpret_cast<float4*>(out + mt_addr(j) + 4 * lane) =
        make_float4(c0, c1, c2, c3);
  }
}

// ---- pass B: boundary combine. 16 WGs x 4 batch columns each.
// Wave w owns j in [64w, 64w+64); lane l loads M[4l..4l+3][j] as dwordx4
// (a full coalesced column slice); x_j broadcast from LDS as float4 over the
// WG's 4 batch columns. Cross-wave reduce via padded LDS (RSTR=20 floats:
// 8 consecutive lanes cover all 32 banks once -> conflict-free b128).
__global__ __launch_bounds__(256) void k_passB(float* __restrict__ out) {
  int bg   = blockIdx.x;             // batch group: columns 4*bg .. 4*bg+3
  int tid  = threadIdx.x;
  int w    = tid >> 6, l = tid & 63;
  __shared__ float xs[NST * 4];         // xs[j*4 + bb] = x_j for column 4bg+bb
  __shared__ float red[4 * 64 * RSTR];  // red[(w*64+l)*RSTR + bb*4 + m]

  *reinterpret_cast<float4*>(&xs[tid * 4]) = make_float4(0.f, 0.f, 0.f, 0.f);
  #pragma unroll
  for (int bb = 0; bb < 4; ++bb)
    out[inc_addr(0, 4 * bg + bb) + tid] = 0.f;   // c_{-1} = 0
  __syncthreads();

  for (int k = 1; k < NCH; ++k) {
    float4 a0 = make_float4(0.f, 0.f, 0.f, 0.f);  // acc for bb=0, comps = m
    float4 a1 = a0, a2 = a0, a3 = a0;
    #pragma unroll 8
    for (int j0 = 0; j0 < 64; ++j0) {
      int j = w * 64 + j0;
      float4 col = *reinterpret_cast<const float4*>(out + mt_addr(j) + 4 * l);
      float4 x4  = *reinterpret_cast<const float4*>(&xs[j * 4]); // LDS broadcast
      a0.x = fmaf(col.x, x4.x, a0.x); a0.y = fmaf(col.y, x4.x, a0.y);
      a0.z = fmaf(col.z, x4.x, a0.z); a0.w = fmaf(col.w, x4.x, a0.w);
      a1.x = fmaf(col.x, x4.y, a1.x); a1.y = fmaf(col.y, x4.y, a1.y);
      a1.z = fmaf(col.z, x4.y, a1.z); a1.w = fmaf(col.w, x4.y, a1.w);
      a2.x = fmaf(col.x, x4.z, a2.x); a2.y = fmaf(col.y, x4.z, a2.y);
      a2.z = fmaf(col.z, x4.z, a2.z); a2.w = fmaf(col.w, x4.z, a2.w);
      a3.x = fmaf(col.x, x4.w, a3.x); a3.y = fmaf(col.y, x4.w, a3.y);
      a3.z = fmaf(col.z, x4.w, a3.z); a3.w = fmaf(col.w, x4.w, a3.w);
    }
    float* rb = &red[(w * 64 + l) * RSTR];
    *reinterpret_cast<float4*>(rb + 0)  = a0;
    *reinterpret_cast<float4*>(rb + 4)  = a1;
    *reinterpret_cast<float4*>(rb + 8)  = a2;
    *reinterpret_cast<float4*>(rb + 12) = a3;
    __syncthreads();
    // wave w finalizes batch column b = 4bg + w, state dims n = 4l..4l+3
    int b = 4 * bg + w;
    float4 y = *reinterpret_cast<const float4*>(out + f_addr(k - 1, b) + 4 * l);
    #pragma unroll
    for (int wp = 0; wp < 4; ++wp) {
      float4 r4 = *reinterpret_cast<const float4*>(&red[(wp * 64 + l) * RSTR + w * 4]);
      y.x += r4.x; y.y += r4.y; y.z += r4.z; y.w += r4.w;
    }
    *reinterpret_cast<float4*>(out + inc_addr(k, b) + 4 * l) = y;
    xs[(4 * l + 0) * 4 + w] = y.x;
    xs[(4 * l + 1) * 4 + w] = y.y;
    xs[(4 * l + 2) * 4 + w] = y.z;
    xs[(4 * l + 3) * 4 + w] = y.w;
    __syncthreads();
  }
}

// ---- pass 3: rerun local scans from true incoming states, store every c_t
__global__ __launch_bounds__(256) void k_pass3(const float* __restrict__ u,
                                               const float* __restrict__ dA,
                                               const float* __restrict__ dB,
                                               float* __restrict__ out) {
  int wid  = blockIdx.x * 4 + (threadIdx.x >> 6);
  int lane = threadIdx.x & 63;
  int k = wid >> 6, b = wid & 63;
  float d[4], p[4], q[4];
  compute_params(lane, dA, d, p, q);
  float4 db = *reinterpret_cast<const float4*>(dB + 4 * lane);
  size_t oa = inc_addr(k, b) + 4 * lane;
  float4 c = *reinterpret_cast<const float4*>(out + oa);  // inc[k][b] (read-then-overwrite)
  float c0 = c.x, c1 = c.y, c2 = c.z, c3 = c.w;
  for (int half = 0; half < CLEN / 64; ++half) {
    float ur = u[(size_t)(k * CLEN + half * 64 + lane) * BATCH + b];
    #pragma unroll 4
    for (int i = 0; i < 64; ++i) {
      float uv = bcast_lane(ur, i);
      hippo_step(c0, c1, c2, c3, d, p, q,
                 db.x * uv, db.y * uv, db.z * uv, db.w * uv);
      // final output, never re-read: nontemporal dwordx4 (skip cache alloc).
      // fx4 (ext_vector_type) -- __builtin_nontemporal_store requires a
      // scalar/vector pointee; HIP's struct float4 is NOT accepted.
      fx4 v; v.x = c0; v.y = c1; v.z = c2; v.w = c3;
      __builtin_nontemporal_store(v, reinterpret_cast<fx4*>(out + oa));
      oa += (size_t)BATCH * NST;     // next t
    }
  }
}

extern "C" void kernel_launch(void* const* d_in, const int* in_sizes, int n_in,
                              void* d_out, int out_size, void* d_ws, size_t ws_size,
                              hipStream_t stream) {
  const float* u  = (const float*)d_in[0];
  const float* dA = (const float*)d_in[1];
  const float* dB = (const float*)d_in[2];
  float* out = (float*)d_out;
  (void)in_sizes; (void)n_in; (void)out_size; (void)d_ws; (void)ws_size;

  k_pass1<<<(NCH * BATCH + NST) / 4, 256, 0, stream>>>(u, dA, dB, out); // 320 blocks
  k_passB<<<BATCH / 4, 256, 0, stream>>>(out);                          // 16 blocks
  k_pass3<<<(NCH * BATCH) / 4, 256, 0, stream>>>(u, dA, dB, out);       // 256 blocks
}